// Round 1
// baseline (306.667 us; speedup 1.0000x reference)
//
#include <hip/hip_runtime.h>
#include <math.h>

#define C 8
#define K 128
#define S 64
#define L 2048
#define NB 64
#define W (L - S + 1)            // 1985
#define TW 128
#define NTW ((W + TW - 1) / TW)  // 16

// Kernel 1: z-normalize shapelets; write transposed [c][s][k] + sum(z^2) per (c,k).
__global__ __launch_bounds__(256) void znorm_kernel(const float* __restrict__ sh,
                                                    float* __restrict__ shz,
                                                    float* __restrict__ sqs) {
  int gid = blockIdx.x * 4 + (threadIdx.x >> 6);  // gid = c*K + k
  int lane = threadIdx.x & 63;
  int c = gid >> 7;
  int k = gid & (K - 1);
  float v = sh[(size_t)gid * S + lane];
  float s1 = v, s2 = v * v;
#pragma unroll
  for (int off = 32; off > 0; off >>= 1) {
    s1 += __shfl_down(s1, off);
    s2 += __shfl_down(s2, off);
  }
  s1 = __shfl(s1, 0);
  s2 = __shfl(s2, 0);
  float mu = s1 * (1.0f / S);
  float sd = sqrtf(fmaxf(s2 * (1.0f / S) - mu * mu, 0.0f));
  float z = (v - mu) / sd;
  shz[((size_t)c * S + lane) * K + k] = z;
  float z2 = z * z;
#pragma unroll
  for (int off = 32; off > 0; off >>= 1) z2 += __shfl_down(z2, off);
  if (lane == 0) sqs[gid] = z2;
}

// Kernel 2: init output to +inf (harness poisons d_out with 0xAA).
__global__ void init_out_kernel(float* __restrict__ out) {
  int i = blockIdx.x * blockDim.x + threadIdx.x;
  if (i < NB * K) out[i] = __int_as_float(0x7F800000);
}

// Kernel 3: main. One block per (w-tile, n). 256 threads = 16(tw) x 16(tk),
// each thread owns an 8w x 8k register tile.
__global__ __launch_bounds__(256) void main_kernel(const float* __restrict__ x,
                                                   const float* __restrict__ shz,
                                                   const float* __restrict__ sqs,
                                                   int* __restrict__ out) {
  __shared__ float sh_lds[S * K];   // [s][k], 32 KB
  __shared__ float x_lds[TW + S];   // 192 floats
  __shared__ float sqx_lds[TW];
  __shared__ float red[16 * 132];   // padded rows to dodge bank conflicts

  const int t = threadIdx.x;
  const int tw = t & 15;
  const int tk = t >> 4;
  const int n = blockIdx.y;
  const int w0 = blockIdx.x * TW;
  const int wb = tw * 8;
  const float* xn = x + (size_t)n * C * L;

  float dsum[8][8];
#pragma unroll
  for (int i = 0; i < 8; ++i)
#pragma unroll
    for (int j = 0; j < 8; ++j) dsum[i][j] = 0.0f;

  for (int c = 0; c < C; ++c) {
    // stage shz[c] (S*K floats = 2048 float4) into LDS
    const float4* src = (const float4*)(shz + (size_t)c * S * K);
    float4* dst = (float4*)sh_lds;
#pragma unroll
    for (int i = 0; i < (S * K / 4) / 256; ++i) dst[t + i * 256] = src[t + i * 256];
    // stage x segment (guard the tail: last tile reads past L, pad 0 — only
    // affects w >= W which are masked out of the min)
    if (t < (TW + S) / 4) {
      int base = w0 + t * 4;
      const float* xc = xn + (size_t)c * L;
      float4 v;
      v.x = (base + 0 < L) ? xc[base + 0] : 0.0f;
      v.y = (base + 1 < L) ? xc[base + 1] : 0.0f;
      v.z = (base + 2 < L) ? xc[base + 2] : 0.0f;
      v.w = (base + 3 < L) ? xc[base + 3] : 0.0f;
      ((float4*)x_lds)[t] = v;
    }
    __syncthreads();
    if (t < TW) {
      float sx = 0.0f;
#pragma unroll
      for (int i = 0; i < S; ++i) {
        float v = x_lds[t + i];
        sx = fmaf(v, v, sx);
      }
      sqx_lds[t] = sx;
    }
    __syncthreads();

    float acc[8][8];
#pragma unroll
    for (int i = 0; i < 8; ++i)
#pragma unroll
      for (int j = 0; j < 8; ++j) acc[i][j] = 0.0f;

    for (int sb = 0; sb < S; sb += 8) {
      float xv[16];
#pragma unroll
      for (int i = 0; i < 16; i += 4)
        *(float4*)&xv[i] = *(const float4*)&x_lds[wb + sb + i];  // wb+sb multiple of 8 -> aligned
#pragma unroll
      for (int sl = 0; sl < 8; ++sl) {
        float shv[8];
        *(float4*)&shv[0] = *(const float4*)&sh_lds[(sb + sl) * K + tk * 8];
        *(float4*)&shv[4] = *(const float4*)&sh_lds[(sb + sl) * K + tk * 8 + 4];
#pragma unroll
        for (int wi = 0; wi < 8; ++wi)
#pragma unroll
          for (int kj = 0; kj < 8; ++kj)
            acc[wi][kj] = fmaf(xv[sl + wi], shv[kj], acc[wi][kj]);
      }
    }

    // fused epilogue for this channel: d = sqrt(max(sq_x + sq_s - 2*cross, eps))
    float sqsk[8];
#pragma unroll
    for (int kj = 0; kj < 8; ++kj) sqsk[kj] = sqs[c * K + tk * 8 + kj];
#pragma unroll
    for (int wi = 0; wi < 8; ++wi) {
      float sxw = sqx_lds[wb + wi];
#pragma unroll
      for (int kj = 0; kj < 8; ++kj) {
        float d2 = sxw + sqsk[kj] - 2.0f * acc[wi][kj];
        dsum[wi][kj] += sqrtf(fmaxf(d2, 1e-12f));
      }
    }
    __syncthreads();  // before next channel overwrites LDS
  }

  // min over this thread's valid w
  float kmin[8];
#pragma unroll
  for (int kj = 0; kj < 8; ++kj) kmin[kj] = __int_as_float(0x7F800000);
#pragma unroll
  for (int wi = 0; wi < 8; ++wi) {
    int w = w0 + wb + wi;
    if (w < W) {
#pragma unroll
      for (int kj = 0; kj < 8; ++kj) kmin[kj] = fminf(kmin[kj], dsum[wi][kj]);
    }
  }
#pragma unroll
  for (int kj = 0; kj < 8; ++kj) red[tw * 132 + tk * 8 + kj] = kmin[kj];
  __syncthreads();
  if (t < K) {
    float m = __int_as_float(0x7F800000);
#pragma unroll
    for (int i = 0; i < 16; ++i) m = fminf(m, red[i * 132 + t]);
    // all values >= 0, so int compare == float compare
    atomicMin(&out[n * K + t], __float_as_int(m));
  }
}

extern "C" void kernel_launch(void* const* d_in, const int* in_sizes, int n_in,
                              void* d_out, int out_size, void* d_ws, size_t ws_size,
                              hipStream_t stream) {
  const float* x = (const float*)d_in[0];    // (64, 8, 2048) fp32
  const float* sh = (const float*)d_in[1];   // (8, 128, 64) fp32
  float* out = (float*)d_out;                // (64, 1, 128) fp32
  float* shz = (float*)d_ws;                 // [C][S][K] floats
  float* sqs = shz + (size_t)C * S * K;      // [C][K] floats

  znorm_kernel<<<C * K / 4, 256, 0, stream>>>(sh, shz, sqs);
  init_out_kernel<<<(NB * K + 255) / 256, 256, 0, stream>>>(out);
  main_kernel<<<dim3(NTW, NB), 256, 0, stream>>>(x, shz, sqs, (int*)out);
}

// Round 2
// 147.020 us; speedup vs baseline: 2.0859x; 2.0859x over previous
//
#include <hip/hip_runtime.h>
#include <math.h>

#define C 8
#define K 128
#define S 64
#define L 2048
#define NB 64
#define W (L - S + 1)   // 1985
#define TW 128
#define NTW 16
#define XCS 200         // padded stride of shifted x copies (bank spread)

typedef __attribute__((ext_vector_type(8))) short bf16x8;
typedef __attribute__((ext_vector_type(4))) float f32x4;

__device__ __forceinline__ unsigned short f2bf(float f) {
  unsigned int u = __float_as_uint(f);
  u += 0x7FFFu + ((u >> 16) & 1u);   // RNE
  return (unsigned short)(u >> 16);
}

// prep: z-normalize shapelets -> bf16 in exact B-fragment order; sum(z^2) fp32;
// also init out to +inf (harness re-poisons d_out with 0xAA every call).
__global__ __launch_bounds__(256) void prep_kernel(const float* __restrict__ sh,
                                                   unsigned short* __restrict__ shzB,
                                                   float* __restrict__ sqs,
                                                   float* __restrict__ out) {
  int tid = blockIdx.x * 256 + threadIdx.x;
  if (tid < NB * K) out[tid] = __int_as_float(0x7F800000);
  int gid = blockIdx.x * 4 + (threadIdx.x >> 6);  // c*K + k
  int lane = threadIdx.x & 63;                    // = s
  float v = sh[(size_t)gid * S + lane];
  float s1 = v, s2 = v * v;
#pragma unroll
  for (int off = 32; off > 0; off >>= 1) {
    s1 += __shfl_down(s1, off);
    s2 += __shfl_down(s2, off);
  }
  s1 = __shfl(s1, 0);
  s2 = __shfl(s2, 0);
  float mu = s1 * (1.0f / S);
  float sd = sqrtf(fmaxf(s2 * (1.0f / S) - mu * mu, 0.0f));
  float z = (v - mu) / sd;
  int c = gid >> 7, k = gid & (K - 1), s = lane;
  // B-frag layout: [(k>>4)][s>>5][lane' = ((s>>3)&3)*16 + (k&15)][s&7]
  int idx = c * 8192 + ((k >> 4) * 2 + (s >> 5)) * 512 +
            ((((s >> 3) & 3) * 16 + (k & 15)) * 8) + (s & 7);
  shzB[idx] = f2bf(z);
  float z2 = z * z;
#pragma unroll
  for (int off = 32; off > 0; off >>= 1) z2 += __shfl_down(z2, off);
  if (lane == 0) sqs[gid] = z2;
}

// main: block = 128 windows x 128 shapelets, 4 waves each 64w x 64k.
__global__ __launch_bounds__(256, 2) void main_kernel(const float* __restrict__ x,
                                                      const unsigned short* __restrict__ shzB,
                                                      const float* __restrict__ sqs,
                                                      int* __restrict__ out) {
  __shared__ __align__(16) unsigned short bbuf[2][8192];   // B double buffer, 16 KB each
  __shared__ __align__(16) unsigned short xcop[C][8][XCS]; // 8 shifted bf16 copies per ch
  __shared__ __align__(16) float sqx[C][TW];

  const int t = threadIdx.x;
  const int lane = t & 63;
  const int wave = t >> 6;
  const int wgrp = wave >> 1;  // 0..1 : w-offset 64
  const int kgrp = wave & 1;   // 0..1 : k-offset 64
  const int col = lane & 15;
  const int quad = lane >> 4;
  const int n = blockIdx.y;
  const int w0 = blockIdx.x * TW;
  const float* xn = x + (size_t)n * C * L;

  // ---- async stage B channel 0 into bbuf[0] (overlaps prologue) ----
  {
    const unsigned short* g = shzB + t * 8;
    unsigned short* lb = &bbuf[0][wave * 512];
#pragma unroll
    for (int i = 0; i < 4; ++i)
      __builtin_amdgcn_global_load_lds(
          (const __attribute__((address_space(1))) void*)(g + i * 2048),
          (__attribute__((address_space(3))) void*)(lb + i * 2048), 16, 0, 0);
  }

  // ---- stage fp32 x segment (8 ch x 192) into scratch = bbuf[1] ----
  float* xf = (float*)&bbuf[1][0];
#pragma unroll
  for (int j = 0; j < 6; ++j) {
    int idx = j * 256 + t;  // < 1536
    int c = idx / 192, e = idx - c * 192;
    int g = w0 + e;
    xf[c * 192 + e] = (g < L) ? xn[c * L + g] : 0.0f;
  }
  __syncthreads();

  // ---- build shifted bf16 copies: copy_r[i] = xseg[i+r] ----
#pragma unroll
  for (int j = 0; j < 24; ++j) {
    int p = (j * 256 + t) * 2;  // even flat index < 12288 = C*8*192
    int c = p / 1536, rem = p - c * 1536;
    int r = rem / 192, i = rem - r * 192;
    int e = i + r;
    float f0 = (e < 192) ? xf[c * 192 + e] : 0.0f;
    float f1 = (e + 1 < 192) ? xf[c * 192 + e + 1] : 0.0f;
    unsigned int pk = (unsigned int)f2bf(f0) | ((unsigned int)f2bf(f1) << 16);
    *(unsigned int*)&xcop[c][r][i] = pk;
  }
  // ---- sliding-window fp32 sqx: thread -> (c, 4 consecutive w) ----
  {
    int c = t >> 5, wl0 = (t & 31) << 2;
    const float* xr = xf + c * 192;
    float s = 0.0f;
#pragma unroll
    for (int si = 0; si < S; ++si) { float v = xr[wl0 + si]; s = fmaf(v, v, s); }
    sqx[c][wl0] = s;
#pragma unroll
    for (int q = 1; q < 4; ++q) {
      float a = xr[wl0 + S - 1 + q], b = xr[wl0 + q - 1];
      s += a * a - b * b;
      sqx[c][wl0 + q] = s;
    }
  }
  __syncthreads();  // xf dead after this; bbuf[1] free for prefetch

  const f32x4 z4 = {0.0f, 0.0f, 0.0f, 0.0f};
  f32x4 dsum[4][4];
#pragma unroll
  for (int a = 0; a < 4; ++a)
#pragma unroll
    for (int b = 0; b < 4; ++b) dsum[a][b] = z4;

  const int m = col;
  const int r = m & 7;

  for (int c = 0; c < C; ++c) {
    // prefetch next channel's B into the other buffer (async, waited at barrier)
    if (c + 1 < C) {
      const unsigned short* g = shzB + (c + 1) * 8192 + t * 8;
      unsigned short* lb = &bbuf[(c + 1) & 1][wave * 512];
#pragma unroll
      for (int i = 0; i < 4; ++i)
        __builtin_amdgcn_global_load_lds(
            (const __attribute__((address_space(1))) void*)(g + i * 2048),
            (__attribute__((address_space(3))) void*)(lb + i * 2048), 16, 0, 0);
    }
    const unsigned short* bb = bbuf[c & 1];
    const unsigned short* xc = &xcop[c][0][0];

    f32x4 acc[4][4];
#pragma unroll
    for (int a = 0; a < 4; ++a)
#pragma unroll
      for (int b = 0; b < 4; ++b) acc[a][b] = z4;

#pragma unroll
    for (int ks = 0; ks < 2; ++ks) {
      bf16x8 bfr[4], afr[4];
#pragma unroll
      for (int kt = 0; kt < 4; ++kt)
        bfr[kt] = *(const bf16x8*)(bb + ((kgrp * 4 + kt) * 2 + ks) * 512 + lane * 8);
#pragma unroll
      for (int wt = 0; wt < 4; ++wt) {
        int i0 = wgrp * 64 + wt * 16 + m + ks * 32 + quad * 8 - r;  // aligned to 8
        afr[wt] = *(const bf16x8*)(xc + r * XCS + i0);
      }
#pragma unroll
      for (int wt = 0; wt < 4; ++wt)
#pragma unroll
        for (int kt = 0; kt < 4; ++kt)
          acc[wt][kt] = __builtin_amdgcn_mfma_f32_16x16x32_bf16(afr[wt], bfr[kt], acc[wt][kt], 0, 0, 0);
    }

    // fused epilogue: dsum += sqrt(max(sqx + sqs - 2*cross, eps))
    float sqsv[4];
#pragma unroll
    for (int kt = 0; kt < 4; ++kt) sqsv[kt] = sqs[c * K + kgrp * 64 + kt * 16 + col];
#pragma unroll
    for (int wt = 0; wt < 4; ++wt) {
      f32x4 sx = *(const f32x4*)&sqx[c][wgrp * 64 + wt * 16 + quad * 4];
#pragma unroll
      for (int kt = 0; kt < 4; ++kt) {
#pragma unroll
        for (int i = 0; i < 4; ++i) {
          float d2 = sx[i] + sqsv[kt] - 2.0f * acc[wt][kt][i];
          dsum[wt][kt][i] += sqrtf(fmaxf(d2, 1e-12f));
        }
      }
    }
    __syncthreads();  // prefetch landed + everyone done with bb
  }

  // min over w (regs -> quad shuffles), then one atomicMin per (k)
  const float INF = __int_as_float(0x7F800000);
  int wbase = w0 + wgrp * 64;
#pragma unroll
  for (int kt = 0; kt < 4; ++kt) {
    float mv = INF;
#pragma unroll
    for (int wt = 0; wt < 4; ++wt)
#pragma unroll
      for (int i = 0; i < 4; ++i) {
        int w = wbase + wt * 16 + quad * 4 + i;
        float v = dsum[wt][kt][i];
        mv = (w < W) ? fminf(mv, v) : mv;
      }
    mv = fminf(mv, __shfl_xor(mv, 16));
    mv = fminf(mv, __shfl_xor(mv, 32));
    if (quad == 0)
      atomicMin(&out[n * K + kgrp * 64 + kt * 16 + col], __float_as_int(mv));
  }
}

extern "C" void kernel_launch(void* const* d_in, const int* in_sizes, int n_in,
                              void* d_out, int out_size, void* d_ws, size_t ws_size,
                              hipStream_t stream) {
  const float* x = (const float*)d_in[0];    // (64, 8, 2048) fp32
  const float* sh = (const float*)d_in[1];   // (8, 128, 64) fp32
  float* out = (float*)d_out;                // (64, 1, 128) fp32
  unsigned short* shzB = (unsigned short*)d_ws;             // 128 KB bf16 B-frag layout
  float* sqs = (float*)((char*)d_ws + C * K * S * 2);       // 4 KB fp32

  prep_kernel<<<256, 256, 0, stream>>>(sh, shzB, sqs, out);
  main_kernel<<<dim3(NTW, NB), 256, 0, stream>>>(x, shzB, sqs, (int*)out);
}

// Round 3
// 98.130 us; speedup vs baseline: 3.1251x; 1.4982x over previous
//
#include <hip/hip_runtime.h>
#include <math.h>

#define C 8
#define K 128
#define S 64
#define L 2048
#define NB 64
#define W (L - S + 1)   // 1985
#define TW 128
#define NTW 16
#define XCS 200         // padded stride of shifted x copies (bank spread)
#define XFS 200         // fp32 x scratch stride (192 data + 8 zero pad)

typedef __attribute__((ext_vector_type(8))) short bf16x8;
typedef __attribute__((ext_vector_type(4))) float f32x4;

__device__ __forceinline__ unsigned short f2bf(float f) {
  unsigned int u = __float_as_uint(f);
  u += 0x7FFFu + ((u >> 16) & 1u);   // RNE
  return (unsigned short)(u >> 16);
}

// prep: z-normalize shapelets -> bf16 in exact B-fragment order; sum(z^2) fp32;
// also init out to +inf (harness re-poisons d_out with 0xAA every call).
__global__ __launch_bounds__(256) void prep_kernel(const float* __restrict__ sh,
                                                   unsigned short* __restrict__ shzB,
                                                   float* __restrict__ sqs,
                                                   float* __restrict__ out) {
  int tid = blockIdx.x * 256 + threadIdx.x;
  if (tid < NB * K) out[tid] = __int_as_float(0x7F800000);
  int gid = blockIdx.x * 4 + (threadIdx.x >> 6);  // c*K + k
  int lane = threadIdx.x & 63;                    // = s
  float v = sh[(size_t)gid * S + lane];
  float s1 = v, s2 = v * v;
#pragma unroll
  for (int off = 32; off > 0; off >>= 1) {
    s1 += __shfl_down(s1, off);
    s2 += __shfl_down(s2, off);
  }
  s1 = __shfl(s1, 0);
  s2 = __shfl(s2, 0);
  float mu = s1 * (1.0f / S);
  float sd = sqrtf(fmaxf(s2 * (1.0f / S) - mu * mu, 0.0f));
  float z = (v - mu) / sd;
  int c = gid >> 7, k = gid & (K - 1), s = lane;
  // B-frag layout: [(k>>4)][s>>5][lane' = ((s>>3)&3)*16 + (k&15)][s&7]
  int idx = c * 8192 + ((k >> 4) * 2 + (s >> 5)) * 512 +
            ((((s >> 3) & 3) * 16 + (k & 15)) * 8) + (s & 7);
  shzB[idx] = f2bf(z);
  float z2 = z * z;
#pragma unroll
  for (int off = 32; off > 0; off >>= 1) z2 += __shfl_down(z2, off);
  if (lane == 0) sqs[gid] = z2;
}

// main: block = 128 windows x 128 shapelets, 4 waves each 64w x 64k.
__global__ __launch_bounds__(256, 2) void main_kernel(const float* __restrict__ x,
                                                      const unsigned short* __restrict__ shzB,
                                                      const float* __restrict__ sqs,
                                                      int* __restrict__ out) {
  __shared__ __align__(16) unsigned short bbuf[2][8192];   // B double buffer, 16 KB each
  __shared__ __align__(16) unsigned short xcop[C][8][XCS]; // 8 shifted bf16 copies per ch
  __shared__ __align__(16) float sqx[C][TW];

  const int t = threadIdx.x;
  const int lane = t & 63;
  const int wave = t >> 6;
  const int wgrp = wave >> 1;  // 0..1 : w-offset 64
  const int kgrp = wave & 1;   // 0..1 : k-offset 64
  const int col = lane & 15;
  const int quad = lane >> 4;
  const int n = blockIdx.y;
  const int w0 = blockIdx.x * TW;
  const float* xn = x + (size_t)n * C * L;

  // ---- async stage B channel 0 into bbuf[0] (overlaps prologue) ----
  {
    const unsigned short* g = shzB + t * 8;
    unsigned short* lb = &bbuf[0][wave * 512];
#pragma unroll
    for (int i = 0; i < 4; ++i)
      __builtin_amdgcn_global_load_lds(
          (const __attribute__((address_space(1))) void*)(g + i * 2048),
          (__attribute__((address_space(3))) void*)(lb + i * 2048), 16, 0, 0);
  }

  // ---- stage fp32 x segment (8 ch x 192, stride 200, zero-padded tail) ----
  float* xf = (float*)&bbuf[1][0];  // C*XFS = 1600 floats, fits in 16 KB scratch
#pragma unroll
  for (int j = 0; j < 7; ++j) {
    int s = j * 256 + t;
    if (s < C * XFS) {
      int c = s / XFS, e = s - c * XFS;
      int g = w0 + e;
      xf[s] = (e < 192 && g < L) ? xn[c * L + g] : 0.0f;
    }
  }
  __syncthreads();

  // ---- build shifted bf16 copies: copy_r[i] = xseg[i+r] (affine indexing) ----
  {
    const int r = t >> 5, q = t & 31;
#pragma unroll
    for (int c = 0; c < C; ++c) {
#pragma unroll
      for (int j = 0; j < 3; ++j) {
        int i = (q + j * 32) * 2;          // even, < 192
        int e = i + r;                      // <= 198 < XFS (pad is zero)
        float f0 = xf[c * XFS + e];
        float f1 = xf[c * XFS + e + 1];
        unsigned int pk = (unsigned int)f2bf(f0) | ((unsigned int)f2bf(f1) << 16);
        *(unsigned int*)&xcop[c][r][i] = pk;
      }
    }
  }
  // ---- sliding-window fp32 sqx: thread -> (c, 4 consecutive w) ----
  {
    int c = t >> 5, wl0 = (t & 31) << 2;
    const float* xr = xf + c * XFS;
    float s = 0.0f;
#pragma unroll
    for (int si = 0; si < S; ++si) { float v = xr[wl0 + si]; s = fmaf(v, v, s); }
    sqx[c][wl0] = s;
#pragma unroll
    for (int q = 1; q < 4; ++q) {
      float a = xr[wl0 + S - 1 + q], b = xr[wl0 + q - 1];
      s += a * a - b * b;
      sqx[c][wl0 + q] = s;
    }
  }
  __syncthreads();  // xf dead after this; bbuf[1] free for prefetch

  const f32x4 z4 = {0.0f, 0.0f, 0.0f, 0.0f};
  f32x4 dsum[4][4];
#pragma unroll
  for (int a = 0; a < 4; ++a)
#pragma unroll
    for (int b = 0; b < 4; ++b) dsum[a][b] = z4;

  const int m = col;
  const int r = m & 7;

  for (int c = 0; c < C; ++c) {
    // prefetch next channel's B into the other buffer (async, waited at barrier)
    if (c + 1 < C) {
      const unsigned short* g = shzB + (c + 1) * 8192 + t * 8;
      unsigned short* lb = &bbuf[(c + 1) & 1][wave * 512];
#pragma unroll
      for (int i = 0; i < 4; ++i)
        __builtin_amdgcn_global_load_lds(
            (const __attribute__((address_space(1))) void*)(g + i * 2048),
            (__attribute__((address_space(3))) void*)(lb + i * 2048), 16, 0, 0);
    }
    const unsigned short* bb = bbuf[c & 1];
    const unsigned short* xc = &xcop[c][0][0];

    f32x4 acc[4][4];
#pragma unroll
    for (int a = 0; a < 4; ++a)
#pragma unroll
      for (int b = 0; b < 4; ++b) acc[a][b] = z4;

#pragma unroll
    for (int ks = 0; ks < 2; ++ks) {
      bf16x8 bfr[4], afr[4];
#pragma unroll
      for (int kt = 0; kt < 4; ++kt)
        bfr[kt] = *(const bf16x8*)(bb + ((kgrp * 4 + kt) * 2 + ks) * 512 + lane * 8);
#pragma unroll
      for (int wt = 0; wt < 4; ++wt) {
        int i0 = wgrp * 64 + wt * 16 + m + ks * 32 + quad * 8 - r;  // aligned to 8
        afr[wt] = *(const bf16x8*)(xc + r * XCS + i0);
      }
#pragma unroll
      for (int wt = 0; wt < 4; ++wt)
#pragma unroll
        for (int kt = 0; kt < 4; ++kt)
          acc[wt][kt] = __builtin_amdgcn_mfma_f32_16x16x32_bf16(afr[wt], bfr[kt], acc[wt][kt], 0, 0, 0);
    }

    // fused epilogue: dsum += v_sqrt(max(sqx + sqs - 2*cross, eps))
    // raw v_sqrt_f32 (~1 ulp) instead of IEEE __ocml_sqrt_f32 (~15-20 instrs)
    float sqsv[4];
#pragma unroll
    for (int kt = 0; kt < 4; ++kt) sqsv[kt] = sqs[c * K + kgrp * 64 + kt * 16 + col];
#pragma unroll
    for (int wt = 0; wt < 4; ++wt) {
      f32x4 sx = *(const f32x4*)&sqx[c][wgrp * 64 + wt * 16 + quad * 4];
#pragma unroll
      for (int kt = 0; kt < 4; ++kt) {
#pragma unroll
        for (int i = 0; i < 4; ++i) {
          float pre = sx[i] + sqsv[kt];
          float d2 = fmaf(-2.0f, acc[wt][kt][i], pre);
          dsum[wt][kt][i] += __builtin_amdgcn_sqrtf(fmaxf(d2, 1e-12f));
        }
      }
    }
    __syncthreads();  // prefetch landed + everyone done with bb
  }

  // min over w (regs -> quad shuffles), then one atomicMin per (k)
  const float INF = __int_as_float(0x7F800000);
  int wbase = w0 + wgrp * 64;
#pragma unroll
  for (int kt = 0; kt < 4; ++kt) {
    float mv = INF;
#pragma unroll
    for (int wt = 0; wt < 4; ++wt)
#pragma unroll
      for (int i = 0; i < 4; ++i) {
        int w = wbase + wt * 16 + quad * 4 + i;
        float v = dsum[wt][kt][i];
        mv = (w < W) ? fminf(mv, v) : mv;
      }
    mv = fminf(mv, __shfl_xor(mv, 16));
    mv = fminf(mv, __shfl_xor(mv, 32));
    if (quad == 0)
      atomicMin(&out[n * K + kgrp * 64 + kt * 16 + col], __float_as_int(mv));
  }
}

extern "C" void kernel_launch(void* const* d_in, const int* in_sizes, int n_in,
                              void* d_out, int out_size, void* d_ws, size_t ws_size,
                              hipStream_t stream) {
  const float* x = (const float*)d_in[0];    // (64, 8, 2048) fp32
  const float* sh = (const float*)d_in[1];   // (8, 128, 64) fp32
  float* out = (float*)d_out;                // (64, 1, 128) fp32
  unsigned short* shzB = (unsigned short*)d_ws;             // 128 KB bf16 B-frag layout
  float* sqs = (float*)((char*)d_ws + C * K * S * 2);       // 4 KB fp32

  prep_kernel<<<256, 256, 0, stream>>>(sh, shzB, sqs, out);
  main_kernel<<<dim3(NTW, NB), 256, 0, stream>>>(x, shzB, sqs, (int*)out);
}